// Round 2
// baseline (308.478 us; speedup 1.0000x reference)
//
#include <hip/hip_runtime.h>
#include <hip/hip_bf16.h>

#define VOCAB 32000
#define DIM 64
#define NB 16
#define SEQ 2048

typedef __attribute__((ext_vector_type(8))) short bf16x8;   // 8 bf16 in 4 VGPRs
typedef __attribute__((ext_vector_type(4))) float f32x4;

// round-to-nearest-even fp32 -> bf16 (inputs are finite normals; no NaN care)
__device__ __forceinline__ unsigned short f2bf(float f) {
    unsigned int u = __builtin_bit_cast(unsigned int, f);
    u = (u + 0x7fffu + ((u >> 16) & 1u)) >> 16;
    return (unsigned short)u;
}

// Gather weight rows per token and convert to bf16.
// One thread per 8 elements: 16*2048 tokens * 8 chunks = 262144 threads.
__global__ __launch_bounds__(256) void gather_cvt(
        const int* __restrict__ seq,
        const float* __restrict__ weight,
        unsigned short* __restrict__ embs) {
    int tid = blockIdx.x * 256 + threadIdx.x;
    int token = tid >> 3;
    int c = (tid & 7) * 8;
    int row = seq[token];
    const float* src = weight + (size_t)row * DIM + c;
    unsigned short o[8];
#pragma unroll
    for (int j = 0; j < 8; ++j) o[j] = f2bf(src[j]);
    *reinterpret_cast<bf16x8*>(embs + (size_t)token * DIM + c) =
        *reinterpret_cast<bf16x8*>(o);
}

// Per batch: C = E * E^T / 8, M=N=2048, K=64 (single k-tile, no LDS).
// WIDE tile: block = 32 rows x 512 cols of C; 4 waves SPLIT COLUMNS
// (wave w covers cols n0+w*128, all waves share the same 32 rows).
// Rationale: each output row gets 2 KB written CONTIGUOUSLY and
// time-correlated (4 waves adjacent) -> DRAM page-hit write streaming,
// vs the old 128x128 tile's 64-128B-per-row scatter at 8KB stride
// (activate-limited). Stores are non-temporal so the 268MB output
// stream doesn't thrash the 4MiB/XCD L2 that holds embs (4MiB).
// Fragment layouts (verified learn_hip m89/m91/m120):
//   A[m=lane&15][k=(lane>>4)*8+j]  -> 16B contiguous per lane from E row
//   B[k=(lane>>4)*8+j][n=lane&15]  -> same pattern from E row (B = E^T)
//   C: col=lane&15, row=(lane>>4)*4+reg
__global__ __launch_bounds__(256) void synergy_gemm(
        const unsigned short* __restrict__ embs,
        float* __restrict__ out) {
    const int b    = blockIdx.z;
    const int wave = threadIdx.x >> 6;
    const int lane = threadIdx.x & 63;
    const int m0   = blockIdx.y * 32;                  // shared by all waves
    const int n0   = blockIdx.x * 512 + wave * 128;    // waves split columns
    const int r    = lane & 15;
    const int q    = lane >> 4;

    const unsigned short* eb = embs + (size_t)b * SEQ * DIM;

    bf16x8 a[2][2], bv[8][2];
#pragma unroll
    for (int mt = 0; mt < 2; ++mt) {
        const unsigned short* p = eb + (size_t)(m0 + mt * 16 + r) * DIM + q * 8;
        a[mt][0] = *reinterpret_cast<const bf16x8*>(p);
        a[mt][1] = *reinterpret_cast<const bf16x8*>(p + 32);
    }
#pragma unroll
    for (int nt = 0; nt < 8; ++nt) {
        const unsigned short* p = eb + (size_t)(n0 + nt * 16 + r) * DIM + q * 8;
        bv[nt][0] = *reinterpret_cast<const bf16x8*>(p);
        bv[nt][1] = *reinterpret_cast<const bf16x8*>(p + 32);
    }

    f32x4 acc[2][8];
#pragma unroll
    for (int mt = 0; mt < 2; ++mt)
#pragma unroll
        for (int nt = 0; nt < 8; ++nt) {
            f32x4 c = {0.f, 0.f, 0.f, 0.f};
            c = __builtin_amdgcn_mfma_f32_16x16x32_bf16(a[mt][0], bv[nt][0], c, 0, 0, 0);
            c = __builtin_amdgcn_mfma_f32_16x16x32_bf16(a[mt][1], bv[nt][1], c, 0, 0, 0);
            acc[mt][nt] = c;
        }

    // Epilogue: direct store, scaled by 1/sqrt(64). Loop order (mt,reg,nt)
    // keeps 8 consecutive store instrs on the SAME 512B row segment ->
    // write-combine + page-hit. Non-temporal: bypass L2 allocation.
    float* ob = out + (size_t)b * SEQ * SEQ;
#pragma unroll
    for (int mt = 0; mt < 2; ++mt)
#pragma unroll
        for (int reg = 0; reg < 4; ++reg) {
            int row = m0 + mt * 16 + q * 4 + reg;
            float* orow = ob + (size_t)row * SEQ + n0;
#pragma unroll
            for (int nt = 0; nt < 8; ++nt)
                __builtin_nontemporal_store(acc[mt][nt][reg] * 0.125f,
                                            &orow[nt * 16 + r]);
        }
}

extern "C" void kernel_launch(void* const* d_in, const int* in_sizes, int n_in,
                              void* d_out, int out_size, void* d_ws, size_t ws_size,
                              hipStream_t stream) {
    const int*   seq    = (const int*)d_in[0];     // [16,2048] int32
    const float* weight = (const float*)d_in[1];   // [32000,64] fp32
    float*       out    = (float*)d_out;           // [16,2048,2048] fp32
    unsigned short* embs = (unsigned short*)d_ws;  // [16,2048,64] bf16 = 4 MiB

    // gather+cvt: 262144 threads
    gather_cvt<<<dim3(262144 / 256), dim3(256), 0, stream>>>(seq, weight, embs);

    // GEMM: grid (n-tiles = 2048/512, m-tiles = 2048/32, batch)
    synergy_gemm<<<dim3(SEQ / 512, SEQ / 32, NB), dim3(256), 0, stream>>>(embs, out);
}

// Round 3
// 283.449 us; speedup vs baseline: 1.0883x; 1.0883x over previous
//
#include <hip/hip_runtime.h>
#include <hip/hip_bf16.h>

#define VOCAB 32000
#define DIM 64
#define NB 16
#define SEQ 2048

typedef __attribute__((ext_vector_type(8))) short bf16x8;   // 8 bf16 in 4 VGPRs
typedef __attribute__((ext_vector_type(4))) float f32x4;

// round-to-nearest-even fp32 -> bf16 (inputs are finite normals; no NaN care)
__device__ __forceinline__ unsigned short f2bf(float f) {
    unsigned int u = __builtin_bit_cast(unsigned int, f);
    u = (u + 0x7fffu + ((u >> 16) & 1u)) >> 16;
    return (unsigned short)u;
}

// Gather weight rows per token and convert to bf16.
// One thread per 8 elements: 16*2048 tokens * 8 chunks = 262144 threads.
__global__ __launch_bounds__(256) void gather_cvt(
        const int* __restrict__ seq,
        const float* __restrict__ weight,
        unsigned short* __restrict__ embs) {
    int tid = blockIdx.x * 256 + threadIdx.x;
    int token = tid >> 3;
    int c = (tid & 7) * 8;
    int row = seq[token];
    const float* src = weight + (size_t)row * DIM + c;
    unsigned short o[8];
#pragma unroll
    for (int j = 0; j < 8; ++j) o[j] = f2bf(src[j]);
    *reinterpret_cast<bf16x8*>(embs + (size_t)token * DIM + c) =
        *reinterpret_cast<bf16x8*>(o);
}

// Per batch: C = E * E^T / 8, M=N=2048, K=64 (single k-tile).
// Block = 128x128 tile, 4 waves, wave w computes rows [m0w, m0w+32).
// C = E*E^T is bit-exactly symmetric, so the block stores its tile
// TRANSPOSED: global rows = n-range, global cols = m-range (coverage over
// the full grid is exact, values bit-identical).
//
// Epilogue: LDS transpose so every global store instruction covers FULL
// 128B L2 lines (the pattern the 6.2TB/s fill kernel uses). Previous
// epilogues all issued 64B segments per instr -> suspected partial-line
// (RFO / sector) penalty on the 268MB write stream.
//   per-wave LDS tile T[128][36] f32 (pad 36: <=2-way banks per phase)
//   T[n][m'] = C[m0w+m'][n0+n]; lane's 4 acc regs -> one ds_write_b128
//   read back row-major: lane i -> row chunk*8+(i>>3), col (i&7)*4
//   global store dwordx4: 8 lanes = one row's 128B line, 8 rows/instr
__global__ __launch_bounds__(256) void synergy_gemm(
        const unsigned short* __restrict__ embs,
        float* __restrict__ out) {
    const int b    = blockIdx.z;
    const int n0   = blockIdx.x * 128;
    const int wave = threadIdx.x >> 6;
    const int lane = threadIdx.x & 63;
    const int m0   = blockIdx.y * 128 + wave * 32;
    const int r    = lane & 15;
    const int q    = lane >> 4;

    __shared__ float lds[4][128][36];   // 72 KiB, wave-private slabs
    float* T = &lds[wave][0][0];

    const unsigned short* eb = embs + (size_t)b * SEQ * DIM;

    bf16x8 a[2][2], bv[8][2];
#pragma unroll
    for (int mt = 0; mt < 2; ++mt) {
        const unsigned short* p = eb + (size_t)(m0 + mt * 16 + r) * DIM + q * 8;
        a[mt][0] = *reinterpret_cast<const bf16x8*>(p);
        a[mt][1] = *reinterpret_cast<const bf16x8*>(p + 32);
    }
#pragma unroll
    for (int nt = 0; nt < 8; ++nt) {
        const unsigned short* p = eb + (size_t)(n0 + nt * 16 + r) * DIM + q * 8;
        bv[nt][0] = *reinterpret_cast<const bf16x8*>(p);
        bv[nt][1] = *reinterpret_cast<const bf16x8*>(p + 32);
    }

    f32x4 acc[2][8];
#pragma unroll
    for (int mt = 0; mt < 2; ++mt)
#pragma unroll
        for (int nt = 0; nt < 8; ++nt) {
            f32x4 c = {0.f, 0.f, 0.f, 0.f};
            c = __builtin_amdgcn_mfma_f32_16x16x32_bf16(a[mt][0], bv[nt][0], c, 0, 0, 0);
            c = __builtin_amdgcn_mfma_f32_16x16x32_bf16(a[mt][1], bv[nt][1], c, 0, 0, 0);
            acc[mt][nt] = c;
        }

    // Stage transposed+scaled fragments into LDS.
    // acc[mt][nt][reg] = C[m0+mt*16+q*4+reg][n0+nt*16+r]
    //   -> T[nt*16+r][mt*16+q*4+reg]
#pragma unroll
    for (int nt = 0; nt < 8; ++nt)
#pragma unroll
        for (int mt = 0; mt < 2; ++mt) {
            f32x4 v = acc[mt][nt] * 0.125f;
            *reinterpret_cast<f32x4*>(T + (nt * 16 + r) * 36 + mt * 16 + q * 4) = v;
        }

    __syncthreads();

    // Read back row-major and store full 128B lines.
    // Wave's transposed tile: global rows [n0, n0+128) x cols [m0, m0+32).
    const int h = lane >> 3;        // 0..7  (row within 8-row group)
    const int l = lane & 7;         // 0..7  (16B column chunk)
    float* ob = out + (size_t)b * SEQ * SEQ + (size_t)m0 + (size_t)l * 4;
#pragma unroll
    for (int chunk = 0; chunk < 16; ++chunk) {
        int trow = chunk * 8 + h;
        f32x4 v = *reinterpret_cast<f32x4*>(T + trow * 36 + l * 4);
        *reinterpret_cast<f32x4*>(ob + (size_t)(n0 + trow) * SEQ) = v;
    }
}

extern "C" void kernel_launch(void* const* d_in, const int* in_sizes, int n_in,
                              void* d_out, int out_size, void* d_ws, size_t ws_size,
                              hipStream_t stream) {
    const int*   seq    = (const int*)d_in[0];     // [16,2048] int32
    const float* weight = (const float*)d_in[1];   // [32000,64] fp32
    float*       out    = (float*)d_out;           // [16,2048,2048] fp32
    unsigned short* embs = (unsigned short*)d_ws;  // [16,2048,64] bf16 = 4 MiB

    // gather+cvt: 262144 threads
    gather_cvt<<<dim3(262144 / 256), dim3(256), 0, stream>>>(seq, weight, embs);

    // GEMM: grid (n-tiles, m-tiles, batch)
    synergy_gemm<<<dim3(SEQ / 128, SEQ / 128, NB), dim3(256), 0, stream>>>(embs, out);
}